// Round 4
// baseline (245.609 us; speedup 1.0000x reference)
//
#include <hip/hip_runtime.h>
#include <math.h>

#define B_ 2
#define C_ 32
#define D_ 32
#define H_ 32
#define W_ 64
#define HW_ (H_*W_)         // 2048
#define DHW_ (D_*H_*W_)     // 65536
#define CDHW_ (C_*DHW_)     // 2097152
#define NSP_ DHW_           // spatial points per batch
#define BN_N_ (B_*DHW_)     // 131072
#define ACC_OFF 16777216    // byte offset of double accumulators in ws (after MT)
#define BORDER 1e-3

// ws: MT [b][p][c] 16MB (after ring-D pass it holds z2 = relu(M - x)), then doubles:
// acc[0..1] norm_sum[b], acc[2..3] norm_sumsq[b],
// acc[4 + r*32 + o]  bn_sum  replica r=0..3, acc[132 + r*32 + o] bn_sumsq. Total 260 doubles.

// ---------------- threshold stats (channel-split: 2 threads per point) ----------------
__global__ __launch_bounds__(256) void k_norm(const float* __restrict__ x, double* __restrict__ acc) {
    int tid = blockIdx.x * 256 + threadIdx.x;       // 262144 threads
    int ln = threadIdx.x & 63;
    int half = ln >> 5, lp = ln & 31;
    int p = (tid >> 6) * 32 + lp;                   // 131072 points, 2x coverage
    int b = p >> 16, pp = p & 65535;
    int d = pp >> 11, h = (pp >> 6) & 31, w = pp & 63;
    int pf = ((d ^ 16) << 11) | ((h ^ 16) << 6) | (w ^ 32);
    const float* xb = x + (size_t)b * CDHW_ + (size_t)half * 16 * DHW_;
    double s = 0.0;
#pragma unroll
    for (int c = 0; c < 16; ++c) {
        float a  = xb[c * DHW_ + pp];
        float bb = xb[c * DHW_ + pf];
        s += fabs((double)a - (double)bb);
    }
    double st = s + __shfl_xor(s, 32, 64);          // full 32-ch sum (both halves hold it)
    double s2 = st * st;
    for (int off = 32; off; off >>= 1) {
        st += __shfl_down(st, off, 64);
        s2 += __shfl_down(s2, off, 64);
    }
    __shared__ double ls[4], ls2[4];
    int wv = threadIdx.x >> 6;
    if (ln == 0) { ls[wv] = st; ls2[wv] = s2; }
    __syncthreads();
    if (threadIdx.x == 0) {                          // each point counted twice -> *0.5 (exact)
        atomicAdd(&acc[0 + b], ((ls[0] + ls[1]) + (ls[2] + ls[3])) * 0.5);
        atomicAdd(&acc[2 + b], ((ls2[0] + ls2[1]) + (ls2[2] + ls2[3])) * 0.5);
    }
}

__device__ __forceinline__ double get_thr(const double* __restrict__ acc, int b) {
    double sum = acc[b], sq = acc[2 + b];
    double n = (double)NSP_;
    double mean = sum / n;
    double var = (sq - sum * sum / n) / (n - 1.0);   // ddof=1
    if (var < 0.0) var = 0.0;
    return mean - sqrt(var);
}

__device__ __forceinline__ float dist32(const float* col, const float* nb) {
    float d0 = 0.f, d1 = 0.f, d2 = 0.f, d3 = 0.f;
#pragma unroll
    for (int c = 0; c < 32; c += 4) {
        d0 += fabsf(col[c+0] - nb[c+0]);
        d1 += fabsf(col[c+1] - nb[c+1]);
        d2 += fabsf(col[c+2] - nb[c+2]);
        d3 += fabsf(col[c+3] - nb[c+3]);
    }
    return (d0 + d1) + (d2 + d3);
}

__device__ __forceinline__ float dist16(const float* col, const float* nb) {
    float d0 = 0.f, d1 = 0.f, d2 = 0.f, d3 = 0.f;
#pragma unroll
    for (int c = 0; c < 16; c += 4) {
        d0 += fabsf(col[c+0] - nb[c+0]);
        d1 += fabsf(col[c+1] - nb[c+1]);
        d2 += fabsf(col[c+2] - nb[c+2]);
        d3 += fabsf(col[c+3] - nb[c+3]);
    }
    return (d0 + d1) + (d2 + d3);
}

__device__ __forceinline__ bool gate(float ds, double thr, const float* col, const float* nb) {
    bool border = fabs((double)ds - thr) < BORDER;
    if (__ballot(border)) {
        double d64 = 0.0;
#pragma unroll
        for (int c = 0; c < 32; ++c) d64 += fabs((double)col[c] - (double)nb[c]);
        return d64 < thr;
    }
    return (double)ds < thr;
}

// ---------------- axis pass along W: one wave per (b,d,h) line, lane = w ----------------
__global__ __launch_bounds__(256) void k_pass_w(const float* __restrict__ x, const double* __restrict__ acc,
                                                float* __restrict__ MT) {
    int wvg = blockIdx.x * 4 + (threadIdx.x >> 6);   // 0..2047 lines
    int ln = threadIdx.x & 63;
    int b = wvg >> 10, d = (wvg >> 5) & 31, h = wvg & 31;
    double thr = get_thr(acc, b);
    const float* base = x + (size_t)b * CDHW_ + d * HW_ + h * W_ + ln;
    float col[32], Mv[32], nb[32];
#pragma unroll
    for (int c = 0; c < 32; ++c) { col[c] = base[c * DHW_]; Mv[c] = col[c]; }
    for (int si = 1; si <= 15; ++si) {
        int srcf = (ln - 2 * si) & 63;
        int srcr = (ln + 2 * si) & 63;
#pragma unroll
        for (int c = 0; c < 32; ++c) nb[c] = __shfl(col[c], srcf, 64);
        float ds = dist32(col, nb);
        bool cmp = gate(ds, thr, col, nb);
#pragma unroll
        for (int c = 0; c < 32; ++c) Mv[c] = (cmp && nb[c] > Mv[c]) ? nb[c] : Mv[c];
        int cr = __shfl(cmp ? 1 : 0, srcr, 64);      // pair symmetry: partner's decision
#pragma unroll
        for (int c = 0; c < 32; ++c) nb[c] = __shfl(col[c], srcr, 64);
        bool cmpr = (cr != 0);
#pragma unroll
        for (int c = 0; c < 32; ++c) Mv[c] = (cmpr && nb[c] > Mv[c]) ? nb[c] : Mv[c];
    }
    {   // s = 16 (w-shift 32): self-paired
#pragma unroll
        for (int c = 0; c < 32; ++c) nb[c] = __shfl(col[c], ln ^ 32, 64);
        float ds = dist32(col, nb);
        bool cmp = gate(ds, thr, col, nb);
#pragma unroll
        for (int c = 0; c < 32; ++c) Mv[c] = (cmp && nb[c] > Mv[c]) ? nb[c] : Mv[c];
    }
    float* mp = MT + ((size_t)b * 65536 + (size_t)d * HW_ + h * W_ + ln) * 32;
#pragma unroll
    for (int q = 0; q < 8; ++q) {
        float4 v; v.x = Mv[4*q]; v.y = Mv[4*q+1]; v.z = Mv[4*q+2]; v.w = Mv[4*q+3];
        *(float4*)(mp + 4 * q) = v;
    }
}

// ---------------- LDS ring pass, channel-split (H or D axis) ----------------
// 512 threads: wl = t&7 (w in tile), half = (t>>3)&1 (16-ch half), pos = (t>>4)&15, par = t>>8.
// 16 rings (par*8+wl) of 16 positions; LDS holds all 32 ch. Z2: final pass writes relu(M - x).
template<int AS, int FS, bool Z2T>
__global__ __launch_bounds__(512) void k_ring(const float* __restrict__ x, const double* __restrict__ acc,
                                              float* __restrict__ MT) {
    __shared__ __align__(16) float L[8192];          // 32 KB
    int t = threadIdx.x;
    int w0 = blockIdx.x * 8;
    int F = blockIdx.y;
    int b = blockIdx.z;
    double thr = get_thr(acc, b);
    const float* xb = x + (size_t)b * CDHW_ + (size_t)F * FS + w0;
#pragma unroll
    for (int it = 0; it < 4; ++it) {
        int f = it * 512 + t;                        // 0..2047 float4s
        int a = f >> 6, c = (f >> 1) & 31, wq = f & 1;
        float4 v = *(const float4*)(xb + (size_t)c * DHW_ + (size_t)a * AS + wq * 4);
        int j = a >> 1, par = a & 1;
        int sl = (((c >> 2) ^ (j & 7)) << 2) + (c & 3);
        int rb = (par * 8 + wq * 4) * 512 + j * 32 + sl;
        L[rb] = v.x; L[rb + 512] = v.y; L[rb + 1024] = v.z; L[rb + 1536] = v.w;
    }
    __syncthreads();
    int wl = t & 7, half = (t >> 3) & 1, pos = (t >> 4) & 15, par = t >> 8;
    int ring = par * 8 + wl;
    const float* Lr = L + ring * 512;
    int qb = half * 4;
    float col[16], Mv[16], nb[16];
#pragma unroll
    for (int k = 0; k < 4; ++k) {
        float4 cv = *(const float4*)(Lr + pos * 32 + (((qb + k) ^ (pos & 7)) << 2));
        col[4*k] = cv.x; col[4*k+1] = cv.y; col[4*k+2] = cv.z; col[4*k+3] = cv.w;
    }
#pragma unroll
    for (int c = 0; c < 16; ++c) Mv[c] = col[c];
    for (int s = 1; s < 16; ++s) {
        int jj = (pos - s) & 15;
#pragma unroll
        for (int k = 0; k < 4; ++k) {
            float4 nv = *(const float4*)(Lr + jj * 32 + (((qb + k) ^ (jj & 7)) << 2));
            nb[4*k] = nv.x; nb[4*k+1] = nv.y; nb[4*k+2] = nv.z; nb[4*k+3] = nv.w;
        }
        float dh = dist16(col, nb);
        float ds = dh + __shfl_xor(dh, 8, 64);       // combine the two 16-ch halves
        bool cmp;
        bool border = fabs((double)ds - thr) < BORDER;
        if (__ballot(border)) {                      // rare fp64 path: exchange f64 partials
            double d64h = 0.0;
#pragma unroll
            for (int c = 0; c < 16; ++c) d64h += fabs((double)col[c] - (double)nb[c]);
            double other = __shfl_xor(d64h, 8, 64);
            cmp = (d64h + other) < thr;
        } else {
            cmp = (double)ds < thr;
        }
#pragma unroll
        for (int c = 0; c < 16; ++c) Mv[c] = (cmp && nb[c] > Mv[c]) ? nb[c] : Mv[c];
    }
    size_t p = (size_t)F * FS + (size_t)(2 * pos + par) * AS + w0 + wl;
    float* mp = MT + ((size_t)b * 65536 + p) * 32 + half * 16;
#pragma unroll
    for (int k = 0; k < 4; ++k) {
        float4 old = *(const float4*)(mp + 4 * k);
        float m0 = fmaxf(old.x, Mv[4*k]);   float m1 = fmaxf(old.y, Mv[4*k+1]);
        float m2 = fmaxf(old.z, Mv[4*k+2]); float m3 = fmaxf(old.w, Mv[4*k+3]);
        float4 o;
        if (Z2T) {   // final pass: store z2 = relu(M - x)
            o.x = fmaxf(m0 - col[4*k],   0.f); o.y = fmaxf(m1 - col[4*k+1], 0.f);
            o.z = fmaxf(m2 - col[4*k+2], 0.f); o.w = fmaxf(m3 - col[4*k+3], 0.f);
        } else {
            o.x = m0; o.y = m1; o.z = m2; o.w = m3;
        }
        *(float4*)(mp + 4 * k) = o;
    }
}

// ---------------- 1x1x1 conv (64 -> 32) + batch stats; 4 waves per 64-point tile ----------------
__global__ __launch_bounds__(256) void k_conv(const float* __restrict__ x, const float* __restrict__ Z2,
                                              const float* __restrict__ w, const float* __restrict__ bias,
                                              float* __restrict__ y, double* __restrict__ acc) {
    int t = threadIdx.x;
    int blk = blockIdx.x;                            // 0..2047
    int b = blk >> 10;
    int p0 = (blk & 1023) * 64;
    int og = t >> 6, pl = t & 63;                    // wave og handles outputs og*8..og*8+7
    const float* xb = x + (size_t)b * CDHW_ + p0 + pl;
    const float4* z2 = (const float4*)(Z2 + ((size_t)b * 65536 + p0 + pl) * 32);
    const float* wo = w + og * 8 * 64;
    float a[8];
#pragma unroll
    for (int k = 0; k < 8; ++k) a[k] = bias[og * 8 + k];
#pragma unroll
    for (int c = 0; c < 32; c += 4) {                // x half (L1-reused across the 4 waves)
        float z0 = xb[(size_t)(c+0) * DHW_];
        float z1 = xb[(size_t)(c+1) * DHW_];
        float zc2 = xb[(size_t)(c+2) * DHW_];
        float z3 = xb[(size_t)(c+3) * DHW_];
#pragma unroll
        for (int k = 0; k < 8; ++k) {
            a[k] = fmaf(wo[k*64 + c+0], z0,  a[k]);
            a[k] = fmaf(wo[k*64 + c+1], z1,  a[k]);
            a[k] = fmaf(wo[k*64 + c+2], zc2, a[k]);
            a[k] = fmaf(wo[k*64 + c+3], z3,  a[k]);
        }
    }
#pragma unroll
    for (int q = 0; q < 8; ++q) {                    // z2 half (contiguous 128B/point)
        float4 v = z2[q];
#pragma unroll
        for (int k = 0; k < 8; ++k) {
            a[k] = fmaf(wo[k*64 + 32 + q*4 + 0], v.x, a[k]);
            a[k] = fmaf(wo[k*64 + 32 + q*4 + 1], v.y, a[k]);
            a[k] = fmaf(wo[k*64 + 32 + q*4 + 2], v.z, a[k]);
            a[k] = fmaf(wo[k*64 + 32 + q*4 + 3], v.w, a[k]);
        }
    }
    float* yb = y + (size_t)b * CDHW_ + p0 + pl;
    int r = blk & 3;
#pragma unroll
    for (int k = 0; k < 8; ++k) {
        yb[(size_t)(og * 8 + k) * DHW_] = a[k];
        float s = a[k], q = a[k] * a[k];
        for (int off = 32; off; off >>= 1) {
            s += __shfl_down(s, off, 64);
            q += __shfl_down(q, off, 64);
        }
        if (pl == 0) {
            atomicAdd(&acc[4   + r * 32 + og * 8 + k], (double)s);
            atomicAdd(&acc[132 + r * 32 + og * 8 + k], (double)q);
        }
    }
}

// ---------------- BN normalize + exact GELU, in-place ----------------
__global__ __launch_bounds__(256) void k_out(float* __restrict__ y, const double* __restrict__ acc,
                                             const float* __restrict__ gamma, const float* __restrict__ beta) {
    int idx = blockIdx.x * 256 + threadIdx.x;       // over 1,048,576 float4
    int elem = idx << 2;
    int o = (elem >> 16) & 31;
    double sm = 0.0, sq = 0.0;
#pragma unroll
    for (int r = 0; r < 4; ++r) { sm += acc[4 + r * 32 + o]; sq += acc[132 + r * 32 + o]; }
    double mu = sm / (double)BN_N_;
    double var = sq / (double)BN_N_ - mu * mu;
    float rstd = (float)(1.0 / sqrt(var + 1e-5));
    float mu_f = (float)mu;
    float g = gamma[o], be = beta[o];
    float4 v = ((const float4*)y)[idx];
    float* vv = (float*)&v;
#pragma unroll
    for (int j = 0; j < 4; ++j) {
        float t = (vv[j] - mu_f) * rstd * g + be;
        vv[j] = 0.5f * t * (1.f + erff(t * 0.70710678118654752f));
    }
    ((float4*)y)[idx] = v;
}

extern "C" void kernel_launch(void* const* d_in, const int* in_sizes, int n_in,
                              void* d_out, int out_size, void* d_ws, size_t ws_size,
                              hipStream_t stream) {
    const float* x     = (const float*)d_in[0];
    const float* w     = (const float*)d_in[1];
    const float* bias  = (const float*)d_in[2];
    const float* gamma = (const float*)d_in[3];
    const float* beta  = (const float*)d_in[4];
    float* out = (float*)d_out;
    float* MT  = (float*)d_ws;                       // [b][p][c]; holds z2 after ring-D
    double* acc = (double*)((char*)d_ws + ACC_OFF);

    hipMemsetAsync(acc, 0, 260 * sizeof(double), stream);
    k_norm  <<<1024, 256, 0, stream>>>(x, acc);
    k_pass_w<<<512, 256, 0, stream>>>(x, acc, MT);
    k_ring<W_,  HW_, false><<<dim3(8, 32, 2), 512, 0, stream>>>(x, acc, MT);   // H pass (F = d)
    k_ring<HW_, W_,  true ><<<dim3(8, 32, 2), 512, 0, stream>>>(x, acc, MT);   // D pass (F = h), writes z2
    k_conv  <<<2048, 256, 0, stream>>>(x, MT, w, bias, out, acc);
    k_out   <<<4096, 256, 0, stream>>>(out, acc, gamma, beta);
}

// Round 5
// 153.572 us; speedup vs baseline: 1.5993x; 1.5993x over previous
//
#include <hip/hip_runtime.h>
#include <math.h>

#define B_ 2
#define C_ 32
#define D_ 32
#define H_ 32
#define W_ 64
#define HW_ (H_*W_)         // 2048
#define DHW_ (D_*H_*W_)     // 65536
#define CDHW_ (C_*DHW_)     // 2097152
#define NSP_ DHW_           // spatial points per batch
#define BN_N_ (B_*DHW_)     // 131072
#define ACC_OFF 16777216    // byte offset of double accumulators in ws (after MT)
#define BORDER 1e-3

// ws: MT [b][p][c] 16MB (after ring-D pass it holds z2 = relu(M - x)), then doubles:
// acc[0..1] norm_sum[b], acc[2..3] norm_sumsq[b], acc[4+o] bn_sum, acc[36+o] bn_sumsq (68 total)

// ---------------- threshold stats (channel-split: 2 threads per point) ----------------
__global__ __launch_bounds__(256) void k_norm(const float* __restrict__ x, double* __restrict__ acc) {
    int tid = blockIdx.x * 256 + threadIdx.x;       // 262144 threads
    int ln = threadIdx.x & 63;
    int half = ln >> 5, lp = ln & 31;
    int p = (tid >> 6) * 32 + lp;                   // 131072 points, 2x coverage
    int b = p >> 16, pp = p & 65535;
    int d = pp >> 11, h = (pp >> 6) & 31, w = pp & 63;
    int pf = ((d ^ 16) << 11) | ((h ^ 16) << 6) | (w ^ 32);
    const float* xb = x + (size_t)b * CDHW_ + (size_t)half * 16 * DHW_;
    double s = 0.0;
#pragma unroll
    for (int c = 0; c < 16; ++c) {
        float a  = xb[c * DHW_ + pp];
        float bb = xb[c * DHW_ + pf];
        s += fabs((double)a - (double)bb);
    }
    double st = s + __shfl_xor(s, 32, 64);          // full 32-ch sum (both halves hold it)
    double s2 = st * st;
    for (int off = 32; off; off >>= 1) {
        st += __shfl_down(st, off, 64);
        s2 += __shfl_down(s2, off, 64);
    }
    __shared__ double ls[4], ls2[4];
    int wv = threadIdx.x >> 6;
    if (ln == 0) { ls[wv] = st; ls2[wv] = s2; }
    __syncthreads();
    if (threadIdx.x == 0) {                          // each point counted twice -> *0.5 (exact)
        atomicAdd(&acc[0 + b], ((ls[0] + ls[1]) + (ls[2] + ls[3])) * 0.5);
        atomicAdd(&acc[2 + b], ((ls2[0] + ls2[1]) + (ls2[2] + ls2[3])) * 0.5);
    }
}

__device__ __forceinline__ double get_thr(const double* __restrict__ acc, int b) {
    double sum = acc[b], sq = acc[2 + b];
    double n = (double)NSP_;
    double mean = sum / n;
    double var = (sq - sum * sum / n) / (n - 1.0);   // ddof=1
    if (var < 0.0) var = 0.0;
    return mean - sqrt(var);
}

__device__ __forceinline__ float dist32(const float* col, const float* nb) {
    float d0 = 0.f, d1 = 0.f, d2 = 0.f, d3 = 0.f;
#pragma unroll
    for (int c = 0; c < 32; c += 4) {
        d0 += fabsf(col[c+0] - nb[c+0]);
        d1 += fabsf(col[c+1] - nb[c+1]);
        d2 += fabsf(col[c+2] - nb[c+2]);
        d3 += fabsf(col[c+3] - nb[c+3]);
    }
    return (d0 + d1) + (d2 + d3);
}

__device__ __forceinline__ float dist16(const float* col, const float* nb) {
    float d0 = 0.f, d1 = 0.f, d2 = 0.f, d3 = 0.f;
#pragma unroll
    for (int c = 0; c < 16; c += 4) {
        d0 += fabsf(col[c+0] - nb[c+0]);
        d1 += fabsf(col[c+1] - nb[c+1]);
        d2 += fabsf(col[c+2] - nb[c+2]);
        d3 += fabsf(col[c+3] - nb[c+3]);
    }
    return (d0 + d1) + (d2 + d3);
}

__device__ __forceinline__ bool gate(float ds, double thr, const float* col, const float* nb) {
    bool border = fabs((double)ds - thr) < BORDER;
    if (__ballot(border)) {
        double d64 = 0.0;
#pragma unroll
        for (int c = 0; c < 32; ++c) d64 += fabs((double)col[c] - (double)nb[c]);
        return d64 < thr;
    }
    return (double)ds < thr;
}

// ---------------- axis pass along W: one wave per (b,d,h) line, lane = w ----------------
__global__ __launch_bounds__(256) void k_pass_w(const float* __restrict__ x, const double* __restrict__ acc,
                                                float* __restrict__ MT) {
    int wvg = blockIdx.x * 4 + (threadIdx.x >> 6);   // 0..2047 lines
    int ln = threadIdx.x & 63;
    int b = wvg >> 10, d = (wvg >> 5) & 31, h = wvg & 31;
    double thr = get_thr(acc, b);
    const float* base = x + (size_t)b * CDHW_ + d * HW_ + h * W_ + ln;
    float col[32], Mv[32], nb[32];
#pragma unroll
    for (int c = 0; c < 32; ++c) { col[c] = base[c * DHW_]; Mv[c] = col[c]; }
    for (int si = 1; si <= 15; ++si) {
        int srcf = (ln - 2 * si) & 63;
        int srcr = (ln + 2 * si) & 63;
#pragma unroll
        for (int c = 0; c < 32; ++c) nb[c] = __shfl(col[c], srcf, 64);
        float ds = dist32(col, nb);
        bool cmp = gate(ds, thr, col, nb);
#pragma unroll
        for (int c = 0; c < 32; ++c) Mv[c] = (cmp && nb[c] > Mv[c]) ? nb[c] : Mv[c];
        int cr = __shfl(cmp ? 1 : 0, srcr, 64);      // pair symmetry: partner's decision
#pragma unroll
        for (int c = 0; c < 32; ++c) nb[c] = __shfl(col[c], srcr, 64);
        bool cmpr = (cr != 0);
#pragma unroll
        for (int c = 0; c < 32; ++c) Mv[c] = (cmpr && nb[c] > Mv[c]) ? nb[c] : Mv[c];
    }
    {   // s = 16 (w-shift 32): self-paired
#pragma unroll
        for (int c = 0; c < 32; ++c) nb[c] = __shfl(col[c], ln ^ 32, 64);
        float ds = dist32(col, nb);
        bool cmp = gate(ds, thr, col, nb);
#pragma unroll
        for (int c = 0; c < 32; ++c) Mv[c] = (cmp && nb[c] > Mv[c]) ? nb[c] : Mv[c];
    }
    float* mp = MT + ((size_t)b * 65536 + (size_t)d * HW_ + h * W_ + ln) * 32;
#pragma unroll
    for (int q = 0; q < 8; ++q) {
        float4 v; v.x = Mv[4*q]; v.y = Mv[4*q+1]; v.z = Mv[4*q+2]; v.w = Mv[4*q+3];
        *(float4*)(mp + 4 * q) = v;
    }
}

// ---------------- LDS ring pass, channel-split (H or D axis) ----------------
template<int AS, int FS, bool Z2T>
__global__ __launch_bounds__(512) void k_ring(const float* __restrict__ x, const double* __restrict__ acc,
                                              float* __restrict__ MT) {
    __shared__ __align__(16) float L[8192];          // 32 KB
    int t = threadIdx.x;
    int w0 = blockIdx.x * 8;
    int F = blockIdx.y;
    int b = blockIdx.z;
    double thr = get_thr(acc, b);
    const float* xb = x + (size_t)b * CDHW_ + (size_t)F * FS + w0;
#pragma unroll
    for (int it = 0; it < 4; ++it) {
        int f = it * 512 + t;                        // 0..2047 float4s
        int a = f >> 6, c = (f >> 1) & 31, wq = f & 1;
        float4 v = *(const float4*)(xb + (size_t)c * DHW_ + (size_t)a * AS + wq * 4);
        int j = a >> 1, par = a & 1;
        int sl = (((c >> 2) ^ (j & 7)) << 2) + (c & 3);
        int rb = (par * 8 + wq * 4) * 512 + j * 32 + sl;
        L[rb] = v.x; L[rb + 512] = v.y; L[rb + 1024] = v.z; L[rb + 1536] = v.w;
    }
    __syncthreads();
    int wl = t & 7, half = (t >> 3) & 1, pos = (t >> 4) & 15, par = t >> 8;
    int ring = par * 8 + wl;
    const float* Lr = L + ring * 512;
    int qb = half * 4;
    float col[16], Mv[16], nb[16];
#pragma unroll
    for (int k = 0; k < 4; ++k) {
        float4 cv = *(const float4*)(Lr + pos * 32 + (((qb + k) ^ (pos & 7)) << 2));
        col[4*k] = cv.x; col[4*k+1] = cv.y; col[4*k+2] = cv.z; col[4*k+3] = cv.w;
    }
#pragma unroll
    for (int c = 0; c < 16; ++c) Mv[c] = col[c];
    for (int s = 1; s < 16; ++s) {
        int jj = (pos - s) & 15;
#pragma unroll
        for (int k = 0; k < 4; ++k) {
            float4 nv = *(const float4*)(Lr + jj * 32 + (((qb + k) ^ (jj & 7)) << 2));
            nb[4*k] = nv.x; nb[4*k+1] = nv.y; nb[4*k+2] = nv.z; nb[4*k+3] = nv.w;
        }
        float dh = dist16(col, nb);
        float ds = dh + __shfl_xor(dh, 8, 64);       // combine the two 16-ch halves
        bool cmp;
        bool border = fabs((double)ds - thr) < BORDER;
        if (__ballot(border)) {                      // rare fp64 path: exchange f64 partials
            double d64h = 0.0;
#pragma unroll
            for (int c = 0; c < 16; ++c) d64h += fabs((double)col[c] - (double)nb[c]);
            double other = __shfl_xor(d64h, 8, 64);
            cmp = (d64h + other) < thr;
        } else {
            cmp = (double)ds < thr;
        }
#pragma unroll
        for (int c = 0; c < 16; ++c) Mv[c] = (cmp && nb[c] > Mv[c]) ? nb[c] : Mv[c];
    }
    size_t p = (size_t)F * FS + (size_t)(2 * pos + par) * AS + w0 + wl;
    float* mp = MT + ((size_t)b * 65536 + p) * 32 + half * 16;
#pragma unroll
    for (int k = 0; k < 4; ++k) {
        float4 old = *(const float4*)(mp + 4 * k);
        float m0 = fmaxf(old.x, Mv[4*k]);   float m1 = fmaxf(old.y, Mv[4*k+1]);
        float m2 = fmaxf(old.z, Mv[4*k+2]); float m3 = fmaxf(old.w, Mv[4*k+3]);
        float4 o;
        if (Z2T) {   // final pass: store z2 = relu(M - x)
            o.x = fmaxf(m0 - col[4*k],   0.f); o.y = fmaxf(m1 - col[4*k+1], 0.f);
            o.z = fmaxf(m2 - col[4*k+2], 0.f); o.w = fmaxf(m3 - col[4*k+3], 0.f);
        } else {
            o.x = m0; o.y = m1; o.z = m2; o.w = m3;
        }
        *(float4*)(mp + 4 * k) = o;
    }
}

// ---------------- 1x1x1 conv (64 -> 32); 4 waves per 64-point tile, 8 outputs/wave ----------------
__global__ __launch_bounds__(256, 4) void k_conv(const float* __restrict__ x, const float* __restrict__ Z2,
                                                 const float* __restrict__ w, const float* __restrict__ bias,
                                                 float* __restrict__ y) {
    int t = threadIdx.x;
    int blk = blockIdx.x;                            // 0..2047
    int b = blk >> 10;
    int p0 = (blk & 1023) * 64;
    int og = __builtin_amdgcn_readfirstlane(t >> 6); // wave-uniform -> weights stay scalar
    int pl = t & 63;
    const float* xb = x + (size_t)b * CDHW_ + p0 + pl;
    const float4* z2 = (const float4*)(Z2 + ((size_t)b * 65536 + p0 + pl) * 32);
    const float* wo = w + og * 8 * 64;               // SGPR base -> s_load weights
    const float* bo = bias + og * 8;
    float a[8];
#pragma unroll
    for (int k = 0; k < 8; ++k) a[k] = bo[k];
#pragma unroll
    for (int c = 0; c < 32; c += 4) {                // x half (L1-reused across the 4 waves)
        float z0 = xb[(size_t)(c+0) * DHW_];
        float z1 = xb[(size_t)(c+1) * DHW_];
        float zc2 = xb[(size_t)(c+2) * DHW_];
        float z3 = xb[(size_t)(c+3) * DHW_];
#pragma unroll
        for (int k = 0; k < 8; ++k) {
            a[k] = fmaf(wo[k*64 + c+0], z0,  a[k]);
            a[k] = fmaf(wo[k*64 + c+1], z1,  a[k]);
            a[k] = fmaf(wo[k*64 + c+2], zc2, a[k]);
            a[k] = fmaf(wo[k*64 + c+3], z3,  a[k]);
        }
    }
#pragma unroll
    for (int q = 0; q < 8; ++q) {                    // z2 half (contiguous 128B/point)
        float4 v = z2[q];
#pragma unroll
        for (int k = 0; k < 8; ++k) {
            a[k] = fmaf(wo[k*64 + 32 + q*4 + 0], v.x, a[k]);
            a[k] = fmaf(wo[k*64 + 32 + q*4 + 1], v.y, a[k]);
            a[k] = fmaf(wo[k*64 + 32 + q*4 + 2], v.z, a[k]);
            a[k] = fmaf(wo[k*64 + 32 + q*4 + 3], v.w, a[k]);
        }
    }
    float* yb = y + (size_t)b * CDHW_ + p0 + pl;
#pragma unroll
    for (int k = 0; k < 8; ++k) yb[(size_t)(og * 8 + k) * DHW_] = a[k];
}

// ---------------- BN batch stats from y ----------------
// grid (16, 32): block = (chunk, o). Each block reads 4096 floats x 2 batches of channel o.
__global__ __launch_bounds__(256) void k_stats(const float* __restrict__ y, double* __restrict__ acc) {
    int o = blockIdx.y, ch = blockIdx.x;
    float s = 0.f, q = 0.f;
#pragma unroll
    for (int b = 0; b < 2; ++b) {
        const float4* yp = (const float4*)(y + (size_t)b * CDHW_ + (size_t)o * DHW_ + ch * 4096);
#pragma unroll
        for (int i = 0; i < 4; ++i) {
            float4 v = yp[i * 256 + threadIdx.x];
            s += ((v.x + v.y) + (v.z + v.w));
            q += ((v.x*v.x + v.y*v.y) + (v.z*v.z + v.w*v.w));
        }
    }
    double sd = s, qd = q;
    for (int off = 32; off; off >>= 1) {
        sd += __shfl_down(sd, off, 64);
        qd += __shfl_down(qd, off, 64);
    }
    __shared__ double ls[4], lq[4];
    int wv = threadIdx.x >> 6;
    if ((threadIdx.x & 63) == 0) { ls[wv] = sd; lq[wv] = qd; }
    __syncthreads();
    if (threadIdx.x == 0) {
        atomicAdd(&acc[4 + o],  (ls[0] + ls[1]) + (ls[2] + ls[3]));
        atomicAdd(&acc[36 + o], (lq[0] + lq[1]) + (lq[2] + lq[3]));
    }
}

// ---------------- BN normalize + exact GELU, in-place ----------------
__global__ __launch_bounds__(256) void k_out(float* __restrict__ y, const double* __restrict__ acc,
                                             const float* __restrict__ gamma, const float* __restrict__ beta) {
    int idx = blockIdx.x * 256 + threadIdx.x;       // over 1,048,576 float4
    int elem = idx << 2;
    int o = (elem >> 16) & 31;
    double mu = acc[4 + o] / (double)BN_N_;
    double var = acc[36 + o] / (double)BN_N_ - mu * mu;
    float rstd = (float)(1.0 / sqrt(var + 1e-5));
    float mu_f = (float)mu;
    float g = gamma[o], be = beta[o];
    float4 v = ((const float4*)y)[idx];
    float* vv = (float*)&v;
#pragma unroll
    for (int j = 0; j < 4; ++j) {
        float t = (vv[j] - mu_f) * rstd * g + be;
        vv[j] = 0.5f * t * (1.f + erff(t * 0.70710678118654752f));
    }
    ((float4*)y)[idx] = v;
}

extern "C" void kernel_launch(void* const* d_in, const int* in_sizes, int n_in,
                              void* d_out, int out_size, void* d_ws, size_t ws_size,
                              hipStream_t stream) {
    const float* x     = (const float*)d_in[0];
    const float* w     = (const float*)d_in[1];
    const float* bias  = (const float*)d_in[2];
    const float* gamma = (const float*)d_in[3];
    const float* beta  = (const float*)d_in[4];
    float* out = (float*)d_out;
    float* MT  = (float*)d_ws;                       // [b][p][c]; holds z2 after ring-D
    double* acc = (double*)((char*)d_ws + ACC_OFF);

    hipMemsetAsync(acc, 0, 68 * sizeof(double), stream);
    k_norm  <<<1024, 256, 0, stream>>>(x, acc);
    k_pass_w<<<512, 256, 0, stream>>>(x, acc, MT);
    k_ring<W_,  HW_, false><<<dim3(8, 32, 2), 512, 0, stream>>>(x, acc, MT);   // H pass (F = d)
    k_ring<HW_, W_,  true ><<<dim3(8, 32, 2), 512, 0, stream>>>(x, acc, MT);   // D pass (F = h), writes z2
    k_conv  <<<2048, 256, 0, stream>>>(x, MT, w, bias, out);
    k_stats <<<dim3(16, 32), 256, 0, stream>>>(out, acc);
    k_out   <<<4096, 256, 0, stream>>>(out, acc, gamma, beta);
}

// Round 6
// 125.686 us; speedup vs baseline: 1.9541x; 1.2219x over previous
//
#include <hip/hip_runtime.h>
#include <math.h>

#define B_ 2
#define C_ 32
#define D_ 32
#define H_ 32
#define W_ 64
#define HW_ (H_*W_)         // 2048
#define DHW_ (D_*H_*W_)     // 65536
#define CDHW_ (C_*DHW_)     // 2097152
#define NSP_ DHW_           // spatial points per batch
#define BN_N_ (B_*DHW_)     // 131072
#define ACC_OFF 16777216    // byte offset of reduction area in ws (after MT)
#define BORDER 1e-3

// ws: MT [b][p][c] 16MB (after ring-D pass holds z2 = relu(M - x)); at ACC_OFF:
//   thr[2]           (double)   - precomputed thresholds, written by k_thr
//   npart[1024]      (double2)  - per-block norm partials {sum, sumsq}, at ACC_OFF+256
//   spart[512]       (double2)  - per-block BN partials {sum, sumsq}, at ACC_OFF+256+16384
// Every slot is written before being read on every call -> no zeroing needed (poison-safe).

// ---------------- threshold stats (channel-split: 2 threads per point) ----------------
__global__ __launch_bounds__(256) void k_norm(const float* __restrict__ x, double2* __restrict__ npart) {
    int tid = blockIdx.x * 256 + threadIdx.x;       // 262144 threads
    int ln = threadIdx.x & 63;
    int half = ln >> 5, lp = ln & 31;
    int p = (tid >> 6) * 32 + lp;                   // 131072 points, 2x coverage
    int b = p >> 16, pp = p & 65535;
    int d = pp >> 11, h = (pp >> 6) & 31, w = pp & 63;
    int pf = ((d ^ 16) << 11) | ((h ^ 16) << 6) | (w ^ 32);
    const float* xb = x + (size_t)b * CDHW_ + (size_t)half * 16 * DHW_;
    double s = 0.0;
#pragma unroll
    for (int c = 0; c < 16; ++c) {
        float a  = xb[c * DHW_ + pp];
        float bb = xb[c * DHW_ + pf];
        s += fabs((double)a - (double)bb);
    }
    double st = s + __shfl_xor(s, 32, 64);          // full 32-ch sum (both halves hold it)
    double s2 = st * st;
    for (int off = 32; off; off >>= 1) {
        st += __shfl_down(st, off, 64);
        s2 += __shfl_down(s2, off, 64);
    }
    __shared__ double ls[4], ls2[4];
    int wv = threadIdx.x >> 6;
    if (ln == 0) { ls[wv] = st; ls2[wv] = s2; }
    __syncthreads();
    if (threadIdx.x == 0) {                          // each point counted twice -> *0.5 (exact)
        double2 o;
        o.x = ((ls[0] + ls[1]) + (ls[2] + ls[3])) * 0.5;
        o.y = ((ls2[0] + ls2[1]) + (ls2[2] + ls2[3])) * 0.5;
        npart[blockIdx.x] = o;
    }
}

// ---------------- reduce norm partials -> thr[2] (one block) ----------------
// blocks 0..511 of k_norm are batch 0, 512..1023 batch 1 (waves 0,1 <-> b=0; 2,3 <-> b=1)
__global__ __launch_bounds__(256) void k_thr(const double2* __restrict__ npart, double* __restrict__ thrp) {
    int t = threadIdx.x;
    double s = 0.0, q = 0.0;
#pragma unroll
    for (int i = 0; i < 4; ++i) {
        double2 v = npart[t * 4 + i];
        s += v.x; q += v.y;
    }
    for (int off = 32; off; off >>= 1) {
        s += __shfl_down(s, off, 64);
        q += __shfl_down(q, off, 64);
    }
    __shared__ double ls[4], lq[4];
    int wv = t >> 6;
    if ((t & 63) == 0) { ls[wv] = s; lq[wv] = q; }
    __syncthreads();
    if (t < 2) {
        double sum = ls[2 * t] + ls[2 * t + 1];
        double sq  = lq[2 * t] + lq[2 * t + 1];
        double n = (double)NSP_;
        double mean = sum / n;
        double var = (sq - sum * sum / n) / (n - 1.0);   // ddof=1
        if (var < 0.0) var = 0.0;
        thrp[t] = mean - sqrt(var);
    }
}

__device__ __forceinline__ float dist32(const float* col, const float* nb) {
    float d0 = 0.f, d1 = 0.f, d2 = 0.f, d3 = 0.f;
#pragma unroll
    for (int c = 0; c < 32; c += 4) {
        d0 += fabsf(col[c+0] - nb[c+0]);
        d1 += fabsf(col[c+1] - nb[c+1]);
        d2 += fabsf(col[c+2] - nb[c+2]);
        d3 += fabsf(col[c+3] - nb[c+3]);
    }
    return (d0 + d1) + (d2 + d3);
}

__device__ __forceinline__ float dist16(const float* col, const float* nb) {
    float d0 = 0.f, d1 = 0.f, d2 = 0.f, d3 = 0.f;
#pragma unroll
    for (int c = 0; c < 16; c += 4) {
        d0 += fabsf(col[c+0] - nb[c+0]);
        d1 += fabsf(col[c+1] - nb[c+1]);
        d2 += fabsf(col[c+2] - nb[c+2]);
        d3 += fabsf(col[c+3] - nb[c+3]);
    }
    return (d0 + d1) + (d2 + d3);
}

__device__ __forceinline__ bool gate(float ds, double thr, const float* col, const float* nb) {
    bool border = fabs((double)ds - thr) < BORDER;
    if (__ballot(border)) {
        double d64 = 0.0;
#pragma unroll
        for (int c = 0; c < 32; ++c) d64 += fabs((double)col[c] - (double)nb[c]);
        return d64 < thr;
    }
    return (double)ds < thr;
}

// ---------------- axis pass along W: one wave per (b,d,h) line, lane = w ----------------
__global__ __launch_bounds__(256) void k_pass_w(const float* __restrict__ x, const double* __restrict__ thrp,
                                                float* __restrict__ MT) {
    int wvg = blockIdx.x * 4 + (threadIdx.x >> 6);   // 0..2047 lines
    int ln = threadIdx.x & 63;
    int b = wvg >> 10, d = (wvg >> 5) & 31, h = wvg & 31;
    double thr = thrp[b];
    const float* base = x + (size_t)b * CDHW_ + d * HW_ + h * W_ + ln;
    float col[32], Mv[32], nb[32];
#pragma unroll
    for (int c = 0; c < 32; ++c) { col[c] = base[c * DHW_]; Mv[c] = col[c]; }
    for (int si = 1; si <= 15; ++si) {
        int srcf = (ln - 2 * si) & 63;
        int srcr = (ln + 2 * si) & 63;
#pragma unroll
        for (int c = 0; c < 32; ++c) nb[c] = __shfl(col[c], srcf, 64);
        float ds = dist32(col, nb);
        bool cmp = gate(ds, thr, col, nb);
#pragma unroll
        for (int c = 0; c < 32; ++c) Mv[c] = (cmp && nb[c] > Mv[c]) ? nb[c] : Mv[c];
        int cr = __shfl(cmp ? 1 : 0, srcr, 64);      // pair symmetry: partner's decision
#pragma unroll
        for (int c = 0; c < 32; ++c) nb[c] = __shfl(col[c], srcr, 64);
        bool cmpr = (cr != 0);
#pragma unroll
        for (int c = 0; c < 32; ++c) Mv[c] = (cmpr && nb[c] > Mv[c]) ? nb[c] : Mv[c];
    }
    {   // s = 16 (w-shift 32): self-paired
#pragma unroll
        for (int c = 0; c < 32; ++c) nb[c] = __shfl(col[c], ln ^ 32, 64);
        float ds = dist32(col, nb);
        bool cmp = gate(ds, thr, col, nb);
#pragma unroll
        for (int c = 0; c < 32; ++c) Mv[c] = (cmp && nb[c] > Mv[c]) ? nb[c] : Mv[c];
    }
    float* mp = MT + ((size_t)b * 65536 + (size_t)d * HW_ + h * W_ + ln) * 32;
#pragma unroll
    for (int q = 0; q < 8; ++q) {
        float4 v; v.x = Mv[4*q]; v.y = Mv[4*q+1]; v.z = Mv[4*q+2]; v.w = Mv[4*q+3];
        *(float4*)(mp + 4 * q) = v;
    }
}

// ---------------- LDS ring pass, channel-split (H or D axis) ----------------
template<int AS, int FS, bool Z2T>
__global__ __launch_bounds__(512) void k_ring(const float* __restrict__ x, const double* __restrict__ thrp,
                                              float* __restrict__ MT) {
    __shared__ __align__(16) float L[8192];          // 32 KB
    int t = threadIdx.x;
    int w0 = blockIdx.x * 8;
    int F = blockIdx.y;
    int b = blockIdx.z;
    double thr = thrp[b];
    const float* xb = x + (size_t)b * CDHW_ + (size_t)F * FS + w0;
#pragma unroll
    for (int it = 0; it < 4; ++it) {
        int f = it * 512 + t;                        // 0..2047 float4s
        int a = f >> 6, c = (f >> 1) & 31, wq = f & 1;
        float4 v = *(const float4*)(xb + (size_t)c * DHW_ + (size_t)a * AS + wq * 4);
        int j = a >> 1, par = a & 1;
        int sl = (((c >> 2) ^ (j & 7)) << 2) + (c & 3);
        int rb = (par * 8 + wq * 4) * 512 + j * 32 + sl;
        L[rb] = v.x; L[rb + 512] = v.y; L[rb + 1024] = v.z; L[rb + 1536] = v.w;
    }
    __syncthreads();
    int wl = t & 7, half = (t >> 3) & 1, pos = (t >> 4) & 15, par = t >> 8;
    int ring = par * 8 + wl;
    const float* Lr = L + ring * 512;
    int qb = half * 4;
    float col[16], Mv[16], nb[16];
#pragma unroll
    for (int k = 0; k < 4; ++k) {
        float4 cv = *(const float4*)(Lr + pos * 32 + (((qb + k) ^ (pos & 7)) << 2));
        col[4*k] = cv.x; col[4*k+1] = cv.y; col[4*k+2] = cv.z; col[4*k+3] = cv.w;
    }
#pragma unroll
    for (int c = 0; c < 16; ++c) Mv[c] = col[c];
    for (int s = 1; s < 16; ++s) {
        int jj = (pos - s) & 15;
#pragma unroll
        for (int k = 0; k < 4; ++k) {
            float4 nv = *(const float4*)(Lr + jj * 32 + (((qb + k) ^ (jj & 7)) << 2));
            nb[4*k] = nv.x; nb[4*k+1] = nv.y; nb[4*k+2] = nv.z; nb[4*k+3] = nv.w;
        }
        float dh = dist16(col, nb);
        float ds = dh + __shfl_xor(dh, 8, 64);       // combine the two 16-ch halves
        bool cmp;
        bool border = fabs((double)ds - thr) < BORDER;
        if (__ballot(border)) {                      // rare fp64 path: exchange f64 partials
            double d64h = 0.0;
#pragma unroll
            for (int c = 0; c < 16; ++c) d64h += fabs((double)col[c] - (double)nb[c]);
            double other = __shfl_xor(d64h, 8, 64);
            cmp = (d64h + other) < thr;
        } else {
            cmp = (double)ds < thr;
        }
#pragma unroll
        for (int c = 0; c < 16; ++c) Mv[c] = (cmp && nb[c] > Mv[c]) ? nb[c] : Mv[c];
    }
    size_t p = (size_t)F * FS + (size_t)(2 * pos + par) * AS + w0 + wl;
    float* mp = MT + ((size_t)b * 65536 + p) * 32 + half * 16;
#pragma unroll
    for (int k = 0; k < 4; ++k) {
        float4 old = *(const float4*)(mp + 4 * k);
        float m0 = fmaxf(old.x, Mv[4*k]);   float m1 = fmaxf(old.y, Mv[4*k+1]);
        float m2 = fmaxf(old.z, Mv[4*k+2]); float m3 = fmaxf(old.w, Mv[4*k+3]);
        float4 o;
        if (Z2T) {   // final pass: store z2 = relu(M - x)
            o.x = fmaxf(m0 - col[4*k],   0.f); o.y = fmaxf(m1 - col[4*k+1], 0.f);
            o.z = fmaxf(m2 - col[4*k+2], 0.f); o.w = fmaxf(m3 - col[4*k+3], 0.f);
        } else {
            o.x = m0; o.y = m1; o.z = m2; o.w = m3;
        }
        *(float4*)(mp + 4 * k) = o;
    }
}

// ---------------- 1x1x1 conv (64 -> 32); 4 waves per 64-point tile, 8 outputs/wave ----------------
__global__ __launch_bounds__(256, 4) void k_conv(const float* __restrict__ x, const float* __restrict__ Z2,
                                                 const float* __restrict__ w, const float* __restrict__ bias,
                                                 float* __restrict__ y) {
    int t = threadIdx.x;
    int blk = blockIdx.x;                            // 0..2047
    int b = blk >> 10;
    int p0 = (blk & 1023) * 64;
    int og = __builtin_amdgcn_readfirstlane(t >> 6); // wave-uniform -> weights stay scalar
    int pl = t & 63;
    const float* xb = x + (size_t)b * CDHW_ + p0 + pl;
    const float4* z2 = (const float4*)(Z2 + ((size_t)b * 65536 + p0 + pl) * 32);
    const float* wo = w + og * 8 * 64;               // SGPR base -> s_load weights
    const float* bo = bias + og * 8;
    float a[8];
#pragma unroll
    for (int k = 0; k < 8; ++k) a[k] = bo[k];
#pragma unroll
    for (int c = 0; c < 32; c += 4) {                // x half (L1-reused across the 4 waves)
        float z0 = xb[(size_t)(c+0) * DHW_];
        float z1 = xb[(size_t)(c+1) * DHW_];
        float zc2 = xb[(size_t)(c+2) * DHW_];
        float z3 = xb[(size_t)(c+3) * DHW_];
#pragma unroll
        for (int k = 0; k < 8; ++k) {
            a[k] = fmaf(wo[k*64 + c+0], z0,  a[k]);
            a[k] = fmaf(wo[k*64 + c+1], z1,  a[k]);
            a[k] = fmaf(wo[k*64 + c+2], zc2, a[k]);
            a[k] = fmaf(wo[k*64 + c+3], z3,  a[k]);
        }
    }
#pragma unroll
    for (int q = 0; q < 8; ++q) {                    // z2 half (contiguous 128B/point)
        float4 v = z2[q];
#pragma unroll
        for (int k = 0; k < 8; ++k) {
            a[k] = fmaf(wo[k*64 + 32 + q*4 + 0], v.x, a[k]);
            a[k] = fmaf(wo[k*64 + 32 + q*4 + 1], v.y, a[k]);
            a[k] = fmaf(wo[k*64 + 32 + q*4 + 2], v.z, a[k]);
            a[k] = fmaf(wo[k*64 + 32 + q*4 + 3], v.w, a[k]);
        }
    }
    float* yb = y + (size_t)b * CDHW_ + p0 + pl;
#pragma unroll
    for (int k = 0; k < 8; ++k) yb[(size_t)(og * 8 + k) * DHW_] = a[k];
}

// ---------------- BN batch stats from y -> per-block partials ----------------
// grid (16, 32): block = (chunk, o). Each block reads 4096 floats x 2 batches of channel o.
__global__ __launch_bounds__(256) void k_stats(const float* __restrict__ y, double2* __restrict__ spart) {
    int o = blockIdx.y, ch = blockIdx.x;
    float s = 0.f, q = 0.f;
#pragma unroll
    for (int b = 0; b < 2; ++b) {
        const float4* yp = (const float4*)(y + (size_t)b * CDHW_ + (size_t)o * DHW_ + ch * 4096);
#pragma unroll
        for (int i = 0; i < 4; ++i) {
            float4 v = yp[i * 256 + threadIdx.x];
            s += ((v.x + v.y) + (v.z + v.w));
            q += ((v.x*v.x + v.y*v.y) + (v.z*v.z + v.w*v.w));
        }
    }
    double sd = s, qd = q;
    for (int off = 32; off; off >>= 1) {
        sd += __shfl_down(sd, off, 64);
        qd += __shfl_down(qd, off, 64);
    }
    __shared__ double ls[4], lq[4];
    int wv = threadIdx.x >> 6;
    if ((threadIdx.x & 63) == 0) { ls[wv] = sd; lq[wv] = qd; }
    __syncthreads();
    if (threadIdx.x == 0) {
        double2 out;
        out.x = (ls[0] + ls[1]) + (ls[2] + ls[3]);
        out.y = (lq[0] + lq[1]) + (lq[2] + lq[3]);
        spart[o * 16 + ch] = out;
    }
}

// ---------------- BN normalize + exact GELU, in-place ----------------
__global__ __launch_bounds__(256) void k_out(float* __restrict__ y, const double2* __restrict__ spart,
                                             const float* __restrict__ gamma, const float* __restrict__ beta) {
    int idx = blockIdx.x * 256 + threadIdx.x;       // over 1,048,576 float4
    int o = (blockIdx.x >> 6) & 31;                  // wave-uniform channel
    double sm = 0.0, sq = 0.0;
#pragma unroll
    for (int ch = 0; ch < 16; ++ch) {
        double2 v = spart[o * 16 + ch];
        sm += v.x; sq += v.y;
    }
    double mu = sm / (double)BN_N_;
    double var = sq / (double)BN_N_ - mu * mu;
    float rstd = (float)(1.0 / sqrt(var + 1e-5));
    float mu_f = (float)mu;
    float g = gamma[o], be = beta[o];
    float4 v = ((const float4*)y)[idx];
    float* vv = (float*)&v;
#pragma unroll
    for (int j = 0; j < 4; ++j) {
        float t = (vv[j] - mu_f) * rstd * g + be;
        vv[j] = 0.5f * t * (1.f + erff(t * 0.70710678118654752f));
    }
    ((float4*)y)[idx] = v;
}

extern "C" void kernel_launch(void* const* d_in, const int* in_sizes, int n_in,
                              void* d_out, int out_size, void* d_ws, size_t ws_size,
                              hipStream_t stream) {
    const float* x     = (const float*)d_in[0];
    const float* w     = (const float*)d_in[1];
    const float* bias  = (const float*)d_in[2];
    const float* gamma = (const float*)d_in[3];
    const float* beta  = (const float*)d_in[4];
    float* out = (float*)d_out;
    float* MT  = (float*)d_ws;                       // [b][p][c]; holds z2 after ring-D
    double*  thrp  = (double*)((char*)d_ws + ACC_OFF);
    double2* npart = (double2*)((char*)d_ws + ACC_OFF + 256);
    double2* spart = (double2*)((char*)d_ws + ACC_OFF + 256 + 16384);

    k_norm  <<<1024, 256, 0, stream>>>(x, npart);
    k_thr   <<<1, 256, 0, stream>>>(npart, thrp);
    k_pass_w<<<512, 256, 0, stream>>>(x, thrp, MT);
    k_ring<W_,  HW_, false><<<dim3(8, 32, 2), 512, 0, stream>>>(x, thrp, MT);   // H pass (F = d)
    k_ring<HW_, W_,  true ><<<dim3(8, 32, 2), 512, 0, stream>>>(x, thrp, MT);   // D pass (F = h), writes z2
    k_conv  <<<2048, 256, 0, stream>>>(x, MT, w, bias, out);
    k_stats <<<dim3(16, 32), 256, 0, stream>>>(out, spart);
    k_out   <<<4096, 256, 0, stream>>>(out, spart, gamma, beta);
}